// Round 8
// baseline (134.970 us; speedup 1.0000x reference)
//
#include <hip/hip_runtime.h>
#include <hip/hip_bf16.h>

#define N 8192
#define D 512

typedef __attribute__((ext_vector_type(8))) short short8;
typedef __attribute__((ext_vector_type(4))) float f32x4;

__device__ __forceinline__ float block_reduce_256(float v, float* red) {
    #pragma unroll
    for (int o = 1; o < 64; o <<= 1) v += __shfl_xor(v, o, 64);
    int w = threadIdx.x >> 6;
    if ((threadIdx.x & 63) == 0) red[w] = v;
    __syncthreads();
    float tot = red[0] + red[1] + red[2] + red[3];
    __syncthreads();
    return tot;
}

// Kernel 1: feature = row_normalize((qf-gf)^2)  [f32 to out, bf16 to ws], sq = rowsum(feature^2)
__global__ void feature_kernel(const float* __restrict__ qf, const float* __restrict__ gf,
                               float* __restrict__ feat, __hip_bfloat16* __restrict__ featb,
                               float* __restrict__ sq) {
    __shared__ float red[4];
    int row = blockIdx.x, t = threadIdx.x;
    const float2* q2 = (const float2*)(qf + (size_t)row * D);
    const float2* g2 = (const float2*)(gf + (size_t)row * D);
    float2 qv = q2[t], gv = g2[t];
    float a = qv.x - gv.x, b = qv.y - gv.y;
    float va = a * a, vb = b * b;
    float rs = block_reduce_256(va + vb, red);
    float inv = (rs == 0.0f) ? 0.0f : 1.0f / rs;
    float fa = va * inv, fb = vb * inv;
    ((float2*)(feat + (size_t)row * D))[t] = make_float2(fa, fb);
    __hip_bfloat162 h;
    h.x = __float2bfloat16(fa);
    h.y = __float2bfloat16(fb);
    ((__hip_bfloat162*)(featb + (size_t)row * D))[t] = h;
    float tot = block_reduce_256(fa * fa + fb * fb, red);
    if (t == 0) sq[row] = tot;
}

// Kernel 2: partial column sums of feature (64 blocks x 128 rows each)
__global__ void colsum_partial_kernel(const float* __restrict__ feat, float* __restrict__ partial) {
    int b = blockIdx.x, t = threadIdx.x;
    const float* fp = feat + (size_t)b * 128 * D;
    float a0 = 0.f, a1 = 0.f;
    for (int r = 0; r < 128; ++r) {
        a0 += fp[r * D + t];
        a1 += fp[r * D + t + 256];
    }
    partial[b * D + t] = a0;
    partial[b * D + t + 256] = a1;
}

// Kernel 3: finalize colsum c[512] and S = sum(sq)
__global__ void finalize_kernel(const float* __restrict__ partial, const float* __restrict__ sq,
                                float* __restrict__ cvec, float* __restrict__ Sval) {
    __shared__ float red[4];
    int t = threadIdx.x;
    if (blockIdx.x == 0) {
        float a0 = 0.f, a1 = 0.f;
        for (int b = 0; b < 64; ++b) {
            a0 += partial[b * D + t];
            a1 += partial[b * D + t + 256];
        }
        cvec[t] = a0;
        cvec[t + 256] = a1;
    } else {
        float s = 0.f;
        for (int k = 0; k < N / 256; ++k) s += sq[t + 256 * k];
        float tot = block_reduce_256(s, red);
        if (t == 0) Sval[0] = tot;
    }
}

// Kernel 4: rowinv_i = 1 / (N*sq_i + S - 2*dot(f_i, c) + 1)
__global__ void rowinv_kernel(const float* __restrict__ feat, const float* __restrict__ sq,
                              const float* __restrict__ cvec, const float* __restrict__ Sval,
                              float* __restrict__ rowinv) {
    __shared__ float red[4];
    int row = blockIdx.x, t = threadIdx.x;
    float2 f = ((const float2*)(feat + (size_t)row * D))[t];
    float2 c = ((const float2*)cvec)[t];
    float dot = block_reduce_256(f.x * c.x + f.y * c.y, red);
    if (t == 0) {
        float rs = (float)N * sq[row] + Sval[0] - 2.0f * dot + 1.0f;
        rowinv[row] = (rs == 0.0f) ? 0.0f : 1.0f / rs;
    }
}

// Kernel 5: full-grid 256x256 tiles (1024 blocks = exactly 4 rounds/CU).
// Rationale vs round-7 symmetric 128^2: MFMA is only ~4% util, so symmetry's
// compute saving is worthless; 256^2 halves L3 panel re-reads (512 MB total),
// drops triangular decode + transpose epilogue + its barrier + tail quant.
// 512 thr (8 waves, 2x4), BK=64 LDS double-buffer (128 KiB, 1 block/CU,
// 2 waves/SIMD), reg-staged (race-safe), one barrier/K-step, T14 prefetch,
// 16B-chunk swizzle c' = c ^ (row&7) on both ds_write and ds_read.
__global__ __launch_bounds__(512, 2) void adj_gemm_kernel(const __hip_bfloat16* __restrict__ featb,
                                                          const float* __restrict__ sq,
                                                          const float* __restrict__ rowinv,
                                                          float* __restrict__ out) {
    __shared__ __align__(16) char lds[131072];  // A dbuf @0/32K, B dbuf @64K/96K
    int wg = blockIdx.x;
    int id = (wg & 7) * 128 + (wg >> 3);  // XCD swizzle, 1024 = 8*128 (bijective)
    int bx = id & 31, by = id >> 5;
    int rowBase = by * 256, colBase = bx * 256;

    int t = threadIdx.x, lane = t & 63, w = t >> 6;
    int wr = w >> 2, wc = w & 3, g = lane >> 4;

    f32x4 acc[8][4];
    #pragma unroll
    for (int m = 0; m < 8; ++m)
        #pragma unroll
        for (int n = 0; n < 4; ++n) acc[m][n] = (f32x4){0.f, 0.f, 0.f, 0.f};

    // staging: tile [256 rows][64 cols bf16] = 2048 x 16B chunks; thread t:
    // chunks t+512q -> row = (t>>3)+64q, 16B col = t&7; swizzled col = col^(row&7)
    int srow = t >> 3, scol = t & 7;
    const __hip_bfloat16* gA = featb + (size_t)(rowBase + srow) * D + scol * 8;
    const __hip_bfloat16* gB = featb + (size_t)(colBase + srow) * D + scol * 8;
    int wo0 = srow * 128 + ((scol ^ (srow & 7)) * 16);  // q-step adds 64*128 bytes, (row&7) invariant

    int arow = wr * 128 + (lane & 15);
    int brow = wc * 64 + (lane & 15);
    int swzc = lane & 7;

    short8 ra[4], rb[4];
    #pragma unroll
    for (int q = 0; q < 4; ++q) {
        ra[q] = *(const short8*)(gA + (size_t)q * 64 * D);
        rb[q] = *(const short8*)(gB + (size_t)q * 64 * D);
    }
    #pragma unroll
    for (int q = 0; q < 4; ++q) {
        *(short8*)(lds + wo0 + q * 8192) = ra[q];
        *(short8*)(lds + 65536 + wo0 + q * 8192) = rb[q];
    }
    __syncthreads();

    int cur = 0;
    for (int ks = 0; ks < 8; ++ks) {
        if (ks < 7) {
            int k0 = (ks + 1) * 64;
            #pragma unroll
            for (int q = 0; q < 4; ++q) {
                ra[q] = *(const short8*)(gA + (size_t)q * 64 * D + k0);
                rb[q] = *(const short8*)(gB + (size_t)q * 64 * D + k0);
            }
        }
        const char* pA = lds + cur * 32768;
        const char* pB = lds + 65536 + cur * 32768;
        #pragma unroll
        for (int kk = 0; kk < 2; ++kk) {
            int ca = ((kk * 4 + g) ^ swzc) * 16;
            short8 bf[4];
            #pragma unroll
            for (int n = 0; n < 4; ++n)
                bf[n] = *(const short8*)(pB + (brow + 16 * n) * 128 + ca);
            #pragma unroll
            for (int m = 0; m < 8; ++m) {
                short8 af = *(const short8*)(pA + (arow + 16 * m) * 128 + ca);
                #pragma unroll
                for (int n = 0; n < 4; ++n)
                    acc[m][n] = __builtin_amdgcn_mfma_f32_16x16x32_bf16(af, bf[n], acc[m][n], 0, 0, 0);
            }
        }
        if (ks < 7) {
            char* wA = lds + (cur ^ 1) * 32768;
            char* wB = lds + 65536 + (cur ^ 1) * 32768;
            #pragma unroll
            for (int q = 0; q < 4; ++q) {
                *(short8*)(wA + wo0 + q * 8192) = ra[q];
                *(short8*)(wB + wo0 + q * 8192) = rb[q];
            }
        }
        __syncthreads();
        cur ^= 1;
    }

    // epilogue: C/D layout col=lane&15 (j), row=g*4+reg (i)
    float sqj[4];
    int jcol[4];
    #pragma unroll
    for (int n = 0; n < 4; ++n) {
        jcol[n] = colBase + wc * 64 + n * 16 + (lane & 15);
        sqj[n] = sq[jcol[n]];
    }
    #pragma unroll
    for (int m = 0; m < 8; ++m) {
        int ibase = rowBase + wr * 128 + m * 16 + g * 4;
        #pragma unroll
        for (int rI = 0; rI < 4; ++rI) {
            int i = ibase + rI;
            float si = sq[i], ri = rowinv[i];
            size_t ro = (size_t)i * N;
            #pragma unroll
            for (int n = 0; n < 4; ++n) {
                float pre = si + sqj[n] - 2.0f * acc[m][n][rI] + (i == jcol[n] ? 1.0f : 0.0f);
                out[ro + jcol[n]] = pre * ri;
            }
        }
    }
}

extern "C" void kernel_launch(void* const* d_in, const int* in_sizes, int n_in,
                              void* d_out, int out_size, void* d_ws, size_t ws_size,
                              hipStream_t stream) {
    const float* qf = (const float*)d_in[0];
    const float* gf = (const float*)d_in[1];
    float* out = (float*)d_out;
    float* feat = out + (size_t)N * N;  // feature output region

    // ws layout (~8.6 MB total)
    char* wsb = (char*)d_ws;
    __hip_bfloat16* featb = (__hip_bfloat16*)wsb;                          // 8 MB bf16 feature
    float* sq      = (float*)(wsb + 8388608);                              // 32 KB
    float* partial = (float*)(wsb + 8388608 + 32768);                      // 128 KB
    float* cvec    = (float*)(wsb + 8388608 + 32768 + 131072);             // 2 KB
    float* Sval    = (float*)(wsb + 8388608 + 32768 + 131072 + 2048);      // 4 B (+pad)
    float* rowinv  = (float*)(wsb + 8388608 + 32768 + 131072 + 2048 + 64); // 32 KB

    feature_kernel<<<N, 256, 0, stream>>>(qf, gf, feat, featb, sq);
    colsum_partial_kernel<<<64, 256, 0, stream>>>(feat, partial);
    finalize_kernel<<<2, 256, 0, stream>>>(partial, sq, cvec, Sval);
    rowinv_kernel<<<N, 256, 0, stream>>>(feat, sq, cvec, Sval, rowinv);
    adj_gemm_kernel<<<1024, 512, 0, stream>>>(featb, sq, rowinv, out);
}